// Round 1
// baseline (425.356 us; speedup 1.0000x reference)
//
#include <hip/hip_runtime.h>
#include <math.h>
#include <stdint.h>

constexpr int kB = 4;
constexpr int kS = 2048;
constexpr int kD = 1024;
constexpr int kH = 16;
constexpr int kHD = 64;

typedef __bf16 bf16;
typedef __attribute__((ext_vector_type(4))) __bf16 bf16x4;
typedef __attribute__((ext_vector_type(8))) __bf16 bf16x8;
typedef __attribute__((ext_vector_type(4))) float f32x4;

__device__ __forceinline__ f32x4 mfma16x16x32(bf16x8 a, bf16x8 b, f32x4 c) {
    return __builtin_amdgcn_mfma_f32_16x16x32_bf16(a, b, c, 0, 0, 0);
}

#if __has_builtin(__builtin_amdgcn_exp2f)
#define EXP2F(x) __builtin_amdgcn_exp2f(x)
#else
#define EXP2F(x) exp2f(x)
#endif

// async 16B global->LDS. lds base must be wave-uniform; HW adds lane*16.
__device__ __forceinline__ void load_lds16(const bf16* g, bf16* lds) {
    __builtin_amdgcn_global_load_lds(
        (const __attribute__((address_space(1))) void*)g,
        (__attribute__((address_space(3))) void*)lds, 16, 0, 0);
}

// ---------------------------------------------------------------------------
// prep_x: fp32 -> bf16 convert of x (8192x1024).
// ---------------------------------------------------------------------------
__global__ __launch_bounds__(256) void prep_x(const float* __restrict__ x,
                                              bf16* __restrict__ xb) {
    size_t i = ((size_t)blockIdx.x * 256 + threadIdx.x) * 8;
    float4 f0 = *(const float4*)(x + i);
    float4 f1 = *(const float4*)(x + i + 4);
    bf16x8 v;
    v[0] = (bf16)f0.x; v[1] = (bf16)f0.y; v[2] = (bf16)f0.z; v[3] = (bf16)f0.w;
    v[4] = (bf16)f1.x; v[5] = (bf16)f1.y; v[6] = (bf16)f1.z; v[7] = (bf16)f1.w;
    *(bf16x8*)(xb + i) = v;
}

// ---------------------------------------------------------------------------
// prep_w: Wt[z*1024 + n][k] = W_z[k][n] * scale_z (bf16, transposed)
// z=0 Wq scaled by 0.125*log2(e) (exp2-domain softmax), 1=Wk, 2=Wv, 3=Wo.
// ---------------------------------------------------------------------------
__global__ __launch_bounds__(256) void prep_w(const float* __restrict__ Wq,
                                              const float* __restrict__ Wk,
                                              const float* __restrict__ Wv,
                                              const float* __restrict__ Wo,
                                              bf16* __restrict__ Wt) {
    __shared__ bf16 t[64 * 72];
    const int z = blockIdx.z;
    const float* W = (z == 0) ? Wq : (z == 1) ? Wk : (z == 2) ? Wv : Wo;
    const float scale = (z == 0) ? 0.18033688011112042f : 1.0f;
    const int k0 = blockIdx.x * 64, n0 = blockIdx.y * 64;
    const int tid = threadIdx.x;
    for (int p = 0; p < 16; ++p) {
        int idx = tid + p * 256;
        int r = idx >> 6, c = idx & 63;
        t[r * 72 + c] = (bf16)(W[(size_t)(k0 + r) * kD + n0 + c] * scale);
    }
    __syncthreads();
    for (int p = 0; p < 16; ++p) {
        int idx = tid + p * 256;
        int r = idx >> 6, c = idx & 63;
        Wt[(size_t)(z * 1024 + n0 + r) * kD + k0 + c] = t[c * 72 + r];
    }
}

// ---------------------------------------------------------------------------
// qkv_gemm: m97 structure. 128x128 tile, BK=64, unpadded LDS, staged via
// global_load_lds width=16.  4 waves 2x2, each 64x64.
// Q,K -> [B,H,S,HD]; V -> transposed [B,H,HD,S].
// ---------------------------------------------------------------------------
__global__ __launch_bounds__(256) void qkv_gemm(
    const bf16* __restrict__ xb, const bf16* __restrict__ Wt,
    bf16* __restrict__ qo, bf16* __restrict__ ko, bf16* __restrict__ vto)
{
    __shared__ bf16 As[128 * 64];
    __shared__ bf16 Bs[128 * 64];

    const int tid  = threadIdx.x;
    const int wave = tid >> 6;
    const int lane = tid & 63;
    const int quad = lane >> 4;
    const int lr   = lane & 15;
    const int wm   = wave >> 1, wn = wave & 1;

    const int m0 = blockIdx.x * 128;
    const int n0 = blockIdx.y * 128;

    const int sr = tid >> 3, sc = tid & 7;   // staging row/16B-block (per p: +32 rows)

    f32x4 acc[4][4];
#pragma unroll
    for (int i = 0; i < 4; ++i)
#pragma unroll
        for (int nt = 0; nt < 4; ++nt) acc[i][nt] = f32x4{0.f, 0.f, 0.f, 0.f};

    for (int k0 = 0; k0 < kD; k0 += 64) {
        __syncthreads();
#pragma unroll
        for (int p = 0; p < 4; ++p) {
            int r = p * 32 + sr;
            load_lds16(&xb[(size_t)(m0 + r) * kD + k0 + sc * 8],
                       &As[(p * 256 + wave * 64) * 8]);
            load_lds16(&Wt[(size_t)(n0 + r) * kD + k0 + sc * 8],
                       &Bs[(p * 256 + wave * 64) * 8]);
        }
        __syncthreads();
#pragma unroll
        for (int kk = 0; kk < 2; ++kk) {
            bf16x8 a[4], b[4];
#pragma unroll
            for (int i = 0; i < 4; ++i)
                a[i] = *(const bf16x8*)&As[(wm * 64 + i * 16 + lr) * 64 + kk * 32 + quad * 8];
#pragma unroll
            for (int nt = 0; nt < 4; ++nt)
                b[nt] = *(const bf16x8*)&Bs[(wn * 64 + nt * 16 + lr) * 64 + kk * 32 + quad * 8];
#pragma unroll
            for (int i = 0; i < 4; ++i)
#pragma unroll
                for (int nt = 0; nt < 4; ++nt)
                    acc[i][nt] = mfma16x16x32(a[i], b[nt], acc[i][nt]);
        }
    }

    const int w_idx = n0 >> 10;               // 0=Q,1=K,2=V (uniform per block)
    if (w_idx < 2) {
        bf16* dst = (w_idx == 0) ? qo : ko;   // [B,H,S,HD]
#pragma unroll
        for (int i = 0; i < 4; ++i)
#pragma unroll
            for (int nt = 0; nt < 4; ++nt) {
                int n   = n0 + wn * 64 + nt * 16 + lr;
                int col = n & 1023, h = col >> 6, hd = col & 63;
#pragma unroll
                for (int j = 0; j < 4; ++j) {
                    int m = m0 + wm * 64 + i * 16 + quad * 4 + j;
                    int b = m >> 11, s = m & 2047;
                    dst[((size_t)(b * kH + h) * kS + s) * kHD + hd] = (bf16)acc[i][nt][j];
                }
            }
    } else {
        // V transposed: [B,H,HD,S]; j walks s -> bf16x4 stores
#pragma unroll
        for (int i = 0; i < 4; ++i)
#pragma unroll
            for (int nt = 0; nt < 4; ++nt) {
                int n   = n0 + wn * 64 + nt * 16 + lr;
                int col = n & 1023, h = col >> 6, hd = col & 63;
                int mb  = m0 + wm * 64 + i * 16 + quad * 4;
                int b = mb >> 11, s = mb & 2047;
                bf16x4 pk;
#pragma unroll
                for (int j = 0; j < 4; ++j) pk[j] = (bf16)acc[i][nt][j];
                *(bf16x4*)&vto[((size_t)(b * kH + h) * kHD + hd) * kS + s] = pk;
            }
    }
}

// ---------------------------------------------------------------------------
// attn v4: causal attention, exp2-domain, unnormalized accumulation.
// Perfect load balance: block = (bh, pair p); the block's TWO waves split each
// row-group's k-tiles by parity (kt = wave, wave+2, ...).  Each block handles
// row-groups r = 63-p and r = p (32 q-rows each); T(r) = r/2+1 tiles, so
// per-block work = 33 tiles for every block, per-wave work = 16 or 17 tiles.
// Parity partials (o, l) combine by addition via an LDS exchange (no running
// max -> sums are order-free).  2048 equal blocks, 8/CU resident, sustained
// 4 waves/SIMD.
// Swapped QK^T (mfma(K,Q)): score fragment holds 4 consecutive keys/lane ->
// P written as ds_write_b64 (8/tile) instead of 32 scattered b16.
// ---------------------------------------------------------------------------
__global__ __launch_bounds__(128, 4) void attn(
    const bf16* __restrict__ q, const bf16* __restrict__ k,
    const bf16* __restrict__ vt, bf16* __restrict__ ctx)
{
    __shared__ bf16 Pl[2][2][32 * 72];   // [wave][buf][qrow*72+key]

    const int tid  = threadIdx.x;
    const int wave = tid >> 6;           // = k-tile parity of this wave
    const int lane = tid & 63;
    const int quad = lane >> 4;
    const int lr   = lane & 15;

    const int bh = blockIdx.x;
    const int p  = blockIdx.y;           // pair index 0..31

    const bf16* qb_p = q  + (size_t)bh * kS * kHD;
    const bf16* kb_p = k  + (size_t)bh * kS * kHD;
    const bf16* vt_p = vt + (size_t)bh * kHD * kS; // [hd][s]

    bf16x8 ones;
#pragma unroll
    for (int i = 0; i < 8; ++i) ones[i] = (bf16)1.0f;

    // per-lane base element offsets
    const size_t koff = (size_t)lr * kHD + quad * 8;   // + k0*64 + nt*1024 + kk*32
    const size_t voff = (size_t)lr * kS + quad * 8;    // + nt*16*2048 + k0 + kk*32
    bf16* Pw = &Pl[wave][0][0];
    float* X = (float*)&Pl[0][0][0];     // exchange buffer (aliases P, used between barriers)

    const int b = bh >> 4;
    const int h = bh & 15;

#pragma unroll 1
    for (int gi = 0; gi < 2; ++gi) {
        const int r    = gi ? p : (63 - p);   // row-group 0..63
        const int T    = (r >> 1) + 1;        // k-tiles for this group
        const int base = r * 32;              // first q-row

        bf16x8 aq[2][2];
#pragma unroll
        for (int g = 0; g < 2; ++g)
#pragma unroll
            for (int kk = 0; kk < 2; ++kk)
                aq[g][kk] = *(const bf16x8*)&qb_p[(size_t)(base + g * 16 + lr) * kHD + kk * 32 + quad * 8];

        f32x4 o[2][4];
        f32x4 lacc[2];
#pragma unroll
        for (int g = 0; g < 2; ++g) {
            lacc[g] = f32x4{0.f, 0.f, 0.f, 0.f};
#pragma unroll
            for (int nt = 0; nt < 4; ++nt) o[g][nt] = f32x4{0.f, 0.f, 0.f, 0.f};
        }

        for (int kt = wave; kt < T; kt += 2) {
            const int k0 = kt * 64;
            bf16* Pb = Pw + ((kt >> 1) & 1) * (32 * 72);

            bf16x8 kf[4][2], vf[4][2];
#pragma unroll
            for (int nt = 0; nt < 4; ++nt) {
                const bf16* kr = kb_p + koff + (size_t)k0 * kHD + nt * 1024;
                kf[nt][0] = *(const bf16x8*)kr;
                kf[nt][1] = *(const bf16x8*)(kr + 32);
                const bf16* vr = vt_p + voff + (size_t)nt * 16 * kS + k0;
                vf[nt][0] = *(const bf16x8*)vr;
                vf[nt][1] = *(const bf16x8*)(vr + 32);
            }

            const bool lastt = (kt == T - 1);
#pragma unroll
            for (int g = 0; g < 2; ++g) {
                // swapped operands: lane holds q-row = base+g*16+lr,
                // keys k0 + nt*16 + quad*4 + j  (4 consecutive keys per reg)
                f32x4 sg[4];
#pragma unroll
                for (int nt = 0; nt < 4; ++nt) {
                    sg[nt] = mfma16x16x32(kf[nt][0], aq[g][0], f32x4{0.f, 0.f, 0.f, 0.f});
                    sg[nt] = mfma16x16x32(kf[nt][1], aq[g][1], sg[nt]);
                }
                if (lastt) {
                    const int qg = base + g * 16 + lr;
#pragma unroll
                    for (int nt = 0; nt < 4; ++nt) {
                        bf16x4 pk;
#pragma unroll
                        for (int j = 0; j < 4; ++j) {
                            float s = sg[nt][j];
                            s = (k0 + nt * 16 + quad * 4 + j > qg) ? -3.0e38f : s;
                            pk[j] = (bf16)EXP2F(s);
                        }
                        *(bf16x4*)&Pb[(g * 16 + lr) * 72 + nt * 16 + quad * 4] = pk;
                    }
                } else {
#pragma unroll
                    for (int nt = 0; nt < 4; ++nt) {
                        bf16x4 pk;
#pragma unroll
                        for (int j = 0; j < 4; ++j) pk[j] = (bf16)EXP2F(sg[nt][j]);
                        *(bf16x4*)&Pb[(g * 16 + lr) * 72 + nt * 16 + quad * 4] = pk;
                    }
                }
            }

            // O += P @ V ; l += P @ ones   (P read back in A-operand layout)
#pragma unroll
            for (int g = 0; g < 2; ++g)
#pragma unroll
                for (int kk = 0; kk < 2; ++kk) {
                    bf16x8 pa = *(const bf16x8*)&Pb[(g * 16 + lr) * 72 + kk * 32 + quad * 8];
                    lacc[g] = mfma16x16x32(pa, ones, lacc[g]);
#pragma unroll
                    for (int nt = 0; nt < 4; ++nt)
                        o[g][nt] = mfma16x16x32(pa, vf[nt][kk], o[g][nt]);
                }
        }

        // ---- combine parity partials: o_total = o0 + o1, l_total = l0 + l1.
        __syncthreads();                     // both waves' k-loops (and LDS reads) done
        if (wave == 1) {
#pragma unroll
            for (int g = 0; g < 2; ++g)
#pragma unroll
                for (int nt = 0; nt < 4; ++nt)
#pragma unroll
                    for (int j = 0; j < 4; ++j)
                        X[((g * 4 + nt) * 4 + j) * 64 + lane] = o[g][nt][j];
#pragma unroll
            for (int g = 0; g < 2; ++g)
#pragma unroll
                for (int j = 0; j < 4; ++j)
                    X[(32 + g * 4 + j) * 64 + lane] = lacc[g][j];
        }
        __syncthreads();
        if (wave == 0) {
#pragma unroll
            for (int g = 0; g < 2; ++g) {
#pragma unroll
                for (int nt = 0; nt < 4; ++nt)
#pragma unroll
                    for (int j = 0; j < 4; ++j)
                        o[g][nt][j] += X[((g * 4 + nt) * 4 + j) * 64 + lane];
#pragma unroll
                for (int j = 0; j < 4; ++j)
                    lacc[g][j] += X[(32 + g * 4 + j) * 64 + lane];
            }
            // ctx [B,S,D] bf16, column h*64+hd
#pragma unroll
            for (int g = 0; g < 2; ++g) {
                float inv[4];
#pragma unroll
                for (int j = 0; j < 4; ++j) inv[j] = 1.0f / lacc[g][j];
#pragma unroll
                for (int nt = 0; nt < 4; ++nt) {
                    int hd = nt * 16 + lr;
#pragma unroll
                    for (int j = 0; j < 4; ++j) {
                        int qg = base + g * 16 + quad * 4 + j;
                        ctx[((size_t)(b * kS + qg)) * kD + h * kHD + hd] = (bf16)(o[g][nt][j] * inv[j]);
                    }
                }
            }
        }
        __syncthreads();                     // protect exchange area before next group's P writes
    }
}

// ---------------------------------------------------------------------------
// out_gemm: out = ctx @ Wo + bo (fp32).  Same m97 structure.
// ---------------------------------------------------------------------------
__global__ __launch_bounds__(256) void out_gemm(
    const bf16* __restrict__ ctxb, const bf16* __restrict__ Wto,
    const float* __restrict__ bo, float* __restrict__ out)
{
    __shared__ bf16 As[128 * 64];
    __shared__ bf16 Bs[128 * 64];

    const int tid  = threadIdx.x;
    const int wave = tid >> 6;
    const int lane = tid & 63;
    const int quad = lane >> 4;
    const int lr   = lane & 15;
    const int wm   = wave >> 1, wn = wave & 1;

    const int m0 = blockIdx.x * 128;
    const int n0 = blockIdx.y * 128;

    const int sr = tid >> 3, sc = tid & 7;

    f32x4 acc[4][4];
#pragma unroll
    for (int i = 0; i < 4; ++i)
#pragma unroll
        for (int nt = 0; nt < 4; ++nt) acc[i][nt] = f32x4{0.f, 0.f, 0.f, 0.f};

    for (int k0 = 0; k0 < kD; k0 += 64) {
        __syncthreads();
#pragma unroll
        for (int p = 0; p < 4; ++p) {
            int r = p * 32 + sr;
            load_lds16(&ctxb[(size_t)(m0 + r) * kD + k0 + sc * 8],
                       &As[(p * 256 + wave * 64) * 8]);
            load_lds16(&Wto[(size_t)(n0 + r) * kD + k0 + sc * 8],
                       &Bs[(p * 256 + wave * 64) * 8]);
        }
        __syncthreads();
#pragma unroll
        for (int kk = 0; kk < 2; ++kk) {
            bf16x8 a[4], b[4];
#pragma unroll
            for (int i = 0; i < 4; ++i)
                a[i] = *(const bf16x8*)&As[(wm * 64 + i * 16 + lr) * 64 + kk * 32 + quad * 8];
#pragma unroll
            for (int nt = 0; nt < 4; ++nt)
                b[nt] = *(const bf16x8*)&Bs[(wn * 64 + nt * 16 + lr) * 64 + kk * 32 + quad * 8];
#pragma unroll
            for (int i = 0; i < 4; ++i)
#pragma unroll
                for (int nt = 0; nt < 4; ++nt)
                    acc[i][nt] = mfma16x16x32(a[i], b[nt], acc[i][nt]);
        }
    }

#pragma unroll
    for (int nt = 0; nt < 4; ++nt) {
        int n = n0 + wn * 64 + nt * 16 + lr;
        float bias = bo[n];
#pragma unroll
        for (int i = 0; i < 4; ++i)
#pragma unroll
            for (int j = 0; j < 4; ++j) {
                int m = m0 + wm * 64 + i * 16 + quad * 4 + j;
                out[(size_t)m * kD + n] = acc[i][nt][j] + bias;
            }
    }
}

// ---------------------------------------------------------------------------
extern "C" void kernel_launch(void* const* d_in, const int* in_sizes, int n_in,
                              void* d_out, int out_size, void* d_ws, size_t ws_size,
                              hipStream_t stream) {
    const float* x  = (const float*)d_in[0];
    const float* Wq = (const float*)d_in[1];
    const float* Wk = (const float*)d_in[2];
    const float* Wv = (const float*)d_in[3];
    const float* Wo = (const float*)d_in[4];
    const float* bo = (const float*)d_in[5];
    float* out = (float*)d_out;

    const size_t n_x   = (size_t)kB * kS * kD;       // 8,388,608
    const size_t n_w   = (size_t)4 * kD * kD;        // 4,194,304
    const size_t n_mat = (size_t)kB * kH * kS * kHD; // 8,388,608

    bf16* xb  = (bf16*)d_ws;        // 16 MB (reused as ctx after qkv_gemm)
    bf16* Wt  = xb + n_x;           // 8 MB
    bf16* Qm  = Wt + n_w;           // 16 MB [B,H,S,HD]
    bf16* Km  = Qm + n_mat;         // 16 MB [B,H,S,HD]
    bf16* Vt  = Km + n_mat;         // 16 MB [B,H,HD,S]
    bf16* ctx = xb;                 // reuse: x dead after qkv_gemm

    prep_x<<<dim3((int)(n_x / (256 * 8))), dim3(256), 0, stream>>>(x, xb);
    prep_w<<<dim3(16, 16, 4), dim3(256), 0, stream>>>(Wq, Wk, Wv, Wo, Wt);
    qkv_gemm<<<dim3(8192 / 128, 3072 / 128), dim3(256), 0, stream>>>(xb, Wt, Qm, Km, Vt);
    attn<<<dim3(kB * kH, 32), dim3(128), 0, stream>>>(Qm, Km, Vt, ctx);
    out_gemm<<<dim3(8192 / 128, 1024 / 128), dim3(256), 0, stream>>>(
        ctx, Wt + (size_t)3 * kD * kD, bo, out);
}

// Round 2
// 324.940 us; speedup vs baseline: 1.3090x; 1.3090x over previous
//
#include <hip/hip_runtime.h>
#include <math.h>
#include <stdint.h>

constexpr int kB = 4;
constexpr int kS = 2048;
constexpr int kD = 1024;
constexpr int kH = 16;
constexpr int kHD = 64;

typedef __bf16 bf16;
typedef __attribute__((ext_vector_type(4))) __bf16 bf16x4;
typedef __attribute__((ext_vector_type(8))) __bf16 bf16x8;
typedef __attribute__((ext_vector_type(4))) float f32x4;

__device__ __forceinline__ f32x4 mfma16x16x32(bf16x8 a, bf16x8 b, f32x4 c) {
    return __builtin_amdgcn_mfma_f32_16x16x32_bf16(a, b, c, 0, 0, 0);
}

#if __has_builtin(__builtin_amdgcn_exp2f)
#define EXP2F(x) __builtin_amdgcn_exp2f(x)
#else
#define EXP2F(x) exp2f(x)
#endif

// async 16B global->LDS. lds base must be wave-uniform; HW adds lane*16.
__device__ __forceinline__ void load_lds16(const bf16* g, bf16* lds) {
    __builtin_amdgcn_global_load_lds(
        (const __attribute__((address_space(1))) void*)g,
        (__attribute__((address_space(3))) void*)lds, 16, 0, 0);
}

// ---------------------------------------------------------------------------
// prep_x: fp32 -> bf16 convert of x (8192x1024).
// ---------------------------------------------------------------------------
__global__ __launch_bounds__(256) void prep_x(const float* __restrict__ x,
                                              bf16* __restrict__ xb) {
    size_t i = ((size_t)blockIdx.x * 256 + threadIdx.x) * 8;
    float4 f0 = *(const float4*)(x + i);
    float4 f1 = *(const float4*)(x + i + 4);
    bf16x8 v;
    v[0] = (bf16)f0.x; v[1] = (bf16)f0.y; v[2] = (bf16)f0.z; v[3] = (bf16)f0.w;
    v[4] = (bf16)f1.x; v[5] = (bf16)f1.y; v[6] = (bf16)f1.z; v[7] = (bf16)f1.w;
    *(bf16x8*)(xb + i) = v;
}

// ---------------------------------------------------------------------------
// prep_w: Wt[z*1024 + n][k] = W_z[k][n] * scale_z (bf16, transposed)
// z=0 Wq scaled by 0.125*log2(e) (exp2-domain softmax), 1=Wk, 2=Wv, 3=Wo.
// ---------------------------------------------------------------------------
__global__ __launch_bounds__(256) void prep_w(const float* __restrict__ Wq,
                                              const float* __restrict__ Wk,
                                              const float* __restrict__ Wv,
                                              const float* __restrict__ Wo,
                                              bf16* __restrict__ Wt) {
    __shared__ bf16 t[64 * 72];
    const int z = blockIdx.z;
    const float* W = (z == 0) ? Wq : (z == 1) ? Wk : (z == 2) ? Wv : Wo;
    const float scale = (z == 0) ? 0.18033688011112042f : 1.0f;
    const int k0 = blockIdx.x * 64, n0 = blockIdx.y * 64;
    const int tid = threadIdx.x;
    for (int p = 0; p < 16; ++p) {
        int idx = tid + p * 256;
        int r = idx >> 6, c = idx & 63;
        t[r * 72 + c] = (bf16)(W[(size_t)(k0 + r) * kD + n0 + c] * scale);
    }
    __syncthreads();
    for (int p = 0; p < 16; ++p) {
        int idx = tid + p * 256;
        int r = idx >> 6, c = idx & 63;
        Wt[(size_t)(z * 1024 + n0 + r) * kD + k0 + c] = t[c * 72 + r];
    }
}

// ---------------------------------------------------------------------------
// qkv_gemm: m97 structure. 128x128 tile, BK=64, unpadded LDS, staged via
// global_load_lds width=16.  4 waves 2x2, each 64x64.
// Q,K -> [B,H,S,HD]; V -> transposed [B,H,HD,S].
// ---------------------------------------------------------------------------
__global__ __launch_bounds__(256) void qkv_gemm(
    const bf16* __restrict__ xb, const bf16* __restrict__ Wt,
    bf16* __restrict__ qo, bf16* __restrict__ ko, bf16* __restrict__ vto)
{
    __shared__ bf16 As[128 * 64];
    __shared__ bf16 Bs[128 * 64];

    const int tid  = threadIdx.x;
    const int wave = tid >> 6;
    const int lane = tid & 63;
    const int quad = lane >> 4;
    const int lr   = lane & 15;
    const int wm   = wave >> 1, wn = wave & 1;

    const int m0 = blockIdx.x * 128;
    const int n0 = blockIdx.y * 128;

    const int sr = tid >> 3, sc = tid & 7;   // staging row/16B-block (per p: +32 rows)

    f32x4 acc[4][4];
#pragma unroll
    for (int i = 0; i < 4; ++i)
#pragma unroll
        for (int nt = 0; nt < 4; ++nt) acc[i][nt] = f32x4{0.f, 0.f, 0.f, 0.f};

    for (int k0 = 0; k0 < kD; k0 += 64) {
        __syncthreads();
#pragma unroll
        for (int p = 0; p < 4; ++p) {
            int r = p * 32 + sr;
            load_lds16(&xb[(size_t)(m0 + r) * kD + k0 + sc * 8],
                       &As[(p * 256 + wave * 64) * 8]);
            load_lds16(&Wt[(size_t)(n0 + r) * kD + k0 + sc * 8],
                       &Bs[(p * 256 + wave * 64) * 8]);
        }
        __syncthreads();
#pragma unroll
        for (int kk = 0; kk < 2; ++kk) {
            bf16x8 a[4], b[4];
#pragma unroll
            for (int i = 0; i < 4; ++i)
                a[i] = *(const bf16x8*)&As[(wm * 64 + i * 16 + lr) * 64 + kk * 32 + quad * 8];
#pragma unroll
            for (int nt = 0; nt < 4; ++nt)
                b[nt] = *(const bf16x8*)&Bs[(wn * 64 + nt * 16 + lr) * 64 + kk * 32 + quad * 8];
#pragma unroll
            for (int i = 0; i < 4; ++i)
#pragma unroll
                for (int nt = 0; nt < 4; ++nt)
                    acc[i][nt] = mfma16x16x32(a[i], b[nt], acc[i][nt]);
        }
    }

    const int w_idx = n0 >> 10;               // 0=Q,1=K,2=V (uniform per block)
    if (w_idx < 2) {
        bf16* dst = (w_idx == 0) ? qo : ko;   // [B,H,S,HD]
#pragma unroll
        for (int i = 0; i < 4; ++i)
#pragma unroll
            for (int nt = 0; nt < 4; ++nt) {
                int n   = n0 + wn * 64 + nt * 16 + lr;
                int col = n & 1023, h = col >> 6, hd = col & 63;
#pragma unroll
                for (int j = 0; j < 4; ++j) {
                    int m = m0 + wm * 64 + i * 16 + quad * 4 + j;
                    int b = m >> 11, s = m & 2047;
                    dst[((size_t)(b * kH + h) * kS + s) * kHD + hd] = (bf16)acc[i][nt][j];
                }
            }
    } else {
        // V transposed: [B,H,HD,S]; j walks s -> bf16x4 stores
#pragma unroll
        for (int i = 0; i < 4; ++i)
#pragma unroll
            for (int nt = 0; nt < 4; ++nt) {
                int n   = n0 + wn * 64 + nt * 16 + lr;
                int col = n & 1023, h = col >> 6, hd = col & 63;
                int mb  = m0 + wm * 64 + i * 16 + quad * 4;
                int b = mb >> 11, s = mb & 2047;
                bf16x4 pk;
#pragma unroll
                for (int j = 0; j < 4; ++j) pk[j] = (bf16)acc[i][nt][j];
                *(bf16x4*)&vto[((size_t)(b * kH + h) * kHD + hd) * kS + s] = pk;
            }
    }
}

// ---------------------------------------------------------------------------
// attn v5: causal attention, exp2-domain, unnormalized accumulation.
// Back to v3's 64-row q-blocks (both waves share every K/V tile -> K/V
// amortized over 64 q-rows, L1/L2 reuse intact, FETCH stays ~30MB).
// Load balance at BLOCK granularity: block (bh, p) processes q-blocks
// 31-p then p sequentially: (32-p)+(p+1) = 33 tiles for EVERY block.
// 1024 equal blocks, all resident (4/CU), no tail.
// Latency fix: register ping-pong prefetch of K fragments (kf(t+1) issued
// during tile t); V(t) issued at tile start, consumed after QK+softmax.
// Swapped QK^T (mfma(K,Q)): P written as bf16x4 (8 ds_write_b64/tile).
// No barriers, no cross-wave combine (each wave owns 32 of the 64 rows).
// ---------------------------------------------------------------------------
#define LOADK(kf, kt_)                                                         \
    do {                                                                       \
        const bf16* krb = kb_p + koff + (size_t)(kt_) * 64 * kHD;              \
        _Pragma("unroll")                                                      \
        for (int nt = 0; nt < 4; ++nt) {                                       \
            kf[nt][0] = *(const bf16x8*)(krb + nt * 1024);                     \
            kf[nt][1] = *(const bf16x8*)(krb + nt * 1024 + 32);                \
        }                                                                      \
    } while (0)

#define LOADV(vf, kt_)                                                         \
    do {                                                                       \
        const bf16* vrb = vt_p + voff + (kt_) * 64;                            \
        _Pragma("unroll")                                                      \
        for (int nt = 0; nt < 4; ++nt) {                                       \
            vf[nt][0] = *(const bf16x8*)(vrb + (size_t)nt * 16 * kS);          \
            vf[nt][1] = *(const bf16x8*)(vrb + (size_t)nt * 16 * kS + 32);     \
        }                                                                      \
    } while (0)

#define COMPUTE(kf, vf, kt_)                                                   \
    do {                                                                       \
        const int k0 = (kt_) * 64;                                             \
        bf16* Pb = Pw + ((kt_) & 1) * (32 * 72);                               \
        const bool lastt = ((kt_) == T - 1);                                   \
        _Pragma("unroll")                                                      \
        for (int g = 0; g < 2; ++g) {                                          \
            f32x4 sg[4];                                                       \
            _Pragma("unroll")                                                  \
            for (int nt = 0; nt < 4; ++nt) {                                   \
                sg[nt] = mfma16x16x32(kf[nt][0], aq[g][0],                     \
                                      f32x4{0.f, 0.f, 0.f, 0.f});              \
                sg[nt] = mfma16x16x32(kf[nt][1], aq[g][1], sg[nt]);            \
            }                                                                  \
            if (lastt) {                                                       \
                const int qg = base + g * 16 + lr;                             \
                _Pragma("unroll")                                              \
                for (int nt = 0; nt < 4; ++nt) {                               \
                    bf16x4 pk;                                                 \
                    _Pragma("unroll")                                          \
                    for (int j = 0; j < 4; ++j) {                              \
                        float s = sg[nt][j];                                   \
                        s = (k0 + nt * 16 + quad * 4 + j > qg) ? -3.0e38f : s; \
                        pk[j] = (bf16)EXP2F(s);                                \
                    }                                                          \
                    *(bf16x4*)&Pb[(g * 16 + lr) * 72 + nt * 16 + quad * 4] = pk; \
                }                                                              \
            } else {                                                           \
                _Pragma("unroll")                                              \
                for (int nt = 0; nt < 4; ++nt) {                               \
                    bf16x4 pk;                                                 \
                    _Pragma("unroll")                                          \
                    for (int j = 0; j < 4; ++j) pk[j] = (bf16)EXP2F(sg[nt][j]); \
                    *(bf16x4*)&Pb[(g * 16 + lr) * 72 + nt * 16 + quad * 4] = pk; \
                }                                                              \
            }                                                                  \
        }                                                                      \
        _Pragma("unroll")                                                      \
        for (int g = 0; g < 2; ++g)                                            \
            _Pragma("unroll")                                                  \
            for (int kk = 0; kk < 2; ++kk) {                                   \
                bf16x8 pa = *(const bf16x8*)&Pb[(g * 16 + lr) * 72 + kk * 32 + quad * 8]; \
                lacc[g] = mfma16x16x32(pa, ones, lacc[g]);                     \
                _Pragma("unroll")                                              \
                for (int nt = 0; nt < 4; ++nt)                                 \
                    o[g][nt] = mfma16x16x32(pa, vf[nt][kk], o[g][nt]);         \
            }                                                                  \
    } while (0)

__global__ __launch_bounds__(128, 2) void attn(
    const bf16* __restrict__ q, const bf16* __restrict__ k,
    const bf16* __restrict__ vt, bf16* __restrict__ ctx)
{
    __shared__ bf16 Pl[2][2][32 * 72];   // [wave][buf][qrow*72+key]

    const int tid  = threadIdx.x;
    const int wave = tid >> 6;
    const int lane = tid & 63;
    const int quad = lane >> 4;
    const int lr   = lane & 15;

    const int bh = blockIdx.x;
    const int p  = blockIdx.y;           // 0..15

    const bf16* qb_p = q  + (size_t)bh * kS * kHD;
    const bf16* kb_p = k  + (size_t)bh * kS * kHD;
    const bf16* vt_p = vt + (size_t)bh * kHD * kS; // [hd][s]

    bf16x8 ones;
#pragma unroll
    for (int i = 0; i < 8; ++i) ones[i] = (bf16)1.0f;

    // per-lane base element offsets
    const size_t koff = (size_t)lr * kHD + quad * 8;   // + kt*64*64 + nt*1024 + kk*32
    const size_t voff = (size_t)lr * kS + quad * 8;    // + nt*16*2048 + kt*64 + kk*32
    bf16* Pw = &Pl[wave][0][0];

    const int b = bh >> 4;
    const int h = bh & 15;

#pragma unroll 1
    for (int gi = 0; gi < 2; ++gi) {
        const int qb   = gi ? p : (31 - p);   // q-block 0..31 (heavy first)
        const int T    = qb + 1;              // k-tiles
        const int base = qb * 64 + wave * 32; // first q-row of this wave

        bf16x8 aq[2][2];
#pragma unroll
        for (int g = 0; g < 2; ++g)
#pragma unroll
            for (int kk = 0; kk < 2; ++kk)
                aq[g][kk] = *(const bf16x8*)&qb_p[(size_t)(base + g * 16 + lr) * kHD + kk * 32 + quad * 8];

        f32x4 o[2][4];
        f32x4 lacc[2];
#pragma unroll
        for (int g = 0; g < 2; ++g) {
            lacc[g] = f32x4{0.f, 0.f, 0.f, 0.f};
#pragma unroll
            for (int nt = 0; nt < 4; ++nt) o[g][nt] = f32x4{0.f, 0.f, 0.f, 0.f};
        }

        bf16x8 kfA[4][2], kfB[4][2];
        LOADK(kfA, 0);
        int kt = 0;
        while (true) {
            {
                bf16x8 vf[4][2];
                LOADV(vf, kt);                       // V(t): ready by PV phase
                if (kt + 1 < T) LOADK(kfB, kt + 1);  // K(t+1): ready next tile
                COMPUTE(kfA, vf, kt);
            }
            if (++kt == T) break;
            {
                bf16x8 vf[4][2];
                LOADV(vf, kt);
                if (kt + 1 < T) LOADK(kfA, kt + 1);
                COMPUTE(kfB, vf, kt);
            }
            if (++kt == T) break;
        }

        // ctx [B,S,D] bf16, column h*64+hd
#pragma unroll
        for (int g = 0; g < 2; ++g) {
            float inv[4];
#pragma unroll
            for (int j = 0; j < 4; ++j) inv[j] = 1.0f / lacc[g][j];
#pragma unroll
            for (int nt = 0; nt < 4; ++nt) {
                int hd = nt * 16 + lr;
#pragma unroll
                for (int j = 0; j < 4; ++j) {
                    int qg = base + g * 16 + quad * 4 + j;
                    ctx[((size_t)(b * kS + qg)) * kD + h * kHD + hd] = (bf16)(o[g][nt][j] * inv[j]);
                }
            }
        }
    }
}

// ---------------------------------------------------------------------------
// out_gemm: out = ctx @ Wo + bo (fp32).  Same m97 structure.
// ---------------------------------------------------------------------------
__global__ __launch_bounds__(256) void out_gemm(
    const bf16* __restrict__ ctxb, const bf16* __restrict__ Wto,
    const float* __restrict__ bo, float* __restrict__ out)
{
    __shared__ bf16 As[128 * 64];
    __shared__ bf16 Bs[128 * 64];

    const int tid  = threadIdx.x;
    const int wave = tid >> 6;
    const int lane = tid & 63;
    const int quad = lane >> 4;
    const int lr   = lane & 15;
    const int wm   = wave >> 1, wn = wave & 1;

    const int m0 = blockIdx.x * 128;
    const int n0 = blockIdx.y * 128;

    const int sr = tid >> 3, sc = tid & 7;

    f32x4 acc[4][4];
#pragma unroll
    for (int i = 0; i < 4; ++i)
#pragma unroll
        for (int nt = 0; nt < 4; ++nt) acc[i][nt] = f32x4{0.f, 0.f, 0.f, 0.f};

    for (int k0 = 0; k0 < kD; k0 += 64) {
        __syncthreads();
#pragma unroll
        for (int p = 0; p < 4; ++p) {
            int r = p * 32 + sr;
            load_lds16(&ctxb[(size_t)(m0 + r) * kD + k0 + sc * 8],
                       &As[(p * 256 + wave * 64) * 8]);
            load_lds16(&Wto[(size_t)(n0 + r) * kD + k0 + sc * 8],
                       &Bs[(p * 256 + wave * 64) * 8]);
        }
        __syncthreads();
#pragma unroll
        for (int kk = 0; kk < 2; ++kk) {
            bf16x8 a[4], b[4];
#pragma unroll
            for (int i = 0; i < 4; ++i)
                a[i] = *(const bf16x8*)&As[(wm * 64 + i * 16 + lr) * 64 + kk * 32 + quad * 8];
#pragma unroll
            for (int nt = 0; nt < 4; ++nt)
                b[nt] = *(const bf16x8*)&Bs[(wn * 64 + nt * 16 + lr) * 64 + kk * 32 + quad * 8];
#pragma unroll
            for (int i = 0; i < 4; ++i)
#pragma unroll
                for (int nt = 0; nt < 4; ++nt)
                    acc[i][nt] = mfma16x16x32(a[i], b[nt], acc[i][nt]);
        }
    }

#pragma unroll
    for (int nt = 0; nt < 4; ++nt) {
        int n = n0 + wn * 64 + nt * 16 + lr;
        float bias = bo[n];
#pragma unroll
        for (int i = 0; i < 4; ++i)
#pragma unroll
            for (int j = 0; j < 4; ++j) {
                int m = m0 + wm * 64 + i * 16 + quad * 4 + j;
                out[(size_t)m * kD + n] = acc[i][nt][j] + bias;
            }
    }
}

// ---------------------------------------------------------------------------
extern "C" void kernel_launch(void* const* d_in, const int* in_sizes, int n_in,
                              void* d_out, int out_size, void* d_ws, size_t ws_size,
                              hipStream_t stream) {
    const float* x  = (const float*)d_in[0];
    const float* Wq = (const float*)d_in[1];
    const float* Wk = (const float*)d_in[2];
    const float* Wv = (const float*)d_in[3];
    const float* Wo = (const float*)d_in[4];
    const float* bo = (const float*)d_in[5];
    float* out = (float*)d_out;

    const size_t n_x   = (size_t)kB * kS * kD;       // 8,388,608
    const size_t n_w   = (size_t)4 * kD * kD;        // 4,194,304
    const size_t n_mat = (size_t)kB * kH * kS * kHD; // 8,388,608

    bf16* xb  = (bf16*)d_ws;        // 16 MB (reused as ctx after qkv_gemm)
    bf16* Wt  = xb + n_x;           // 8 MB
    bf16* Qm  = Wt + n_w;           // 16 MB [B,H,S,HD]
    bf16* Km  = Qm + n_mat;         // 16 MB [B,H,S,HD]
    bf16* Vt  = Km + n_mat;         // 16 MB [B,H,HD,S]
    bf16* ctx = xb;                 // reuse: x dead after qkv_gemm

    prep_x<<<dim3((int)(n_x / (256 * 8))), dim3(256), 0, stream>>>(x, xb);
    prep_w<<<dim3(16, 16, 4), dim3(256), 0, stream>>>(Wq, Wk, Wv, Wo, Wt);
    qkv_gemm<<<dim3(8192 / 128, 3072 / 128), dim3(256), 0, stream>>>(xb, Wt, Qm, Km, Vt);
    attn<<<dim3(kB * kH, 16), dim3(128), 0, stream>>>(Qm, Km, Vt, ctx);
    out_gemm<<<dim3(8192 / 128, 1024 / 128), dim3(256), 0, stream>>>(
        ctx, Wt + (size_t)3 * kD * kD, bo, out);
}